// Round 12
// baseline (78.767 us; speedup 1.0000x reference)
//
#include <hip/hip_runtime.h>

typedef __bf16 bf16x8 __attribute__((ext_vector_type(8)));
typedef __bf16 bf16x2 __attribute__((ext_vector_type(2)));
typedef float  f32x4  __attribute__((ext_vector_type(4)));

// ws layout (bytes). All A-operand fragments lane-linear:
// one frag = 1024 B; lane l's 16 B at frag_base + l*16 (coalesced dwordx4).
//   WT0 : 8 frags   (nt 0..7, K=32 zero-padded)      [0      .. 8191  ]
//   WTH : 160 frags ((h*4+ks)*8 + nt)                [8192   .. 172031]
//   WLT : 8 frags   (ks 0..3 real, 4..7 zero pad)    [172032 .. 180223]
#define WS_WT0_B 0
#define WS_WTH_B 8192
#define WS_WLT_B 172032

__device__ __forceinline__ unsigned short f2b(float f) {
  return __builtin_bit_cast(unsigned short, (__bf16)f);
}

__global__ void prep_kernel(const float* __restrict__ W0,
                            const float* __restrict__ Wh,
                            const float* __restrict__ WL,
                            unsigned short* __restrict__ ws) {
  int i = blockIdx.x * 256 + threadIdx.x;   // ushort index == byte/2
  int l  = (i >> 3) & 63;                   // lane within frag
  int j  = i & 7;                           // element within lane's 8
  int lm = l & 15, lh = l >> 4;
  if (i < 4096) {                           // WT0
    int nt = i >> 9;
    int n = nt * 16 + lm, k = lh * 8 + j;
    ws[i] = f2b(k < 4 ? W0[k * 128 + n] : 0.f);
  } else if (i < 86016) {                   // WTH
    int t = i - 4096;
    int frag = t >> 9;                      // (h*4+ks)*8 + nt
    int nt = frag & 7, ks = (frag >> 3) & 3, h = frag >> 5;
    int n = nt * 16 + lm, k = ks * 32 + lh * 8 + j;
    ws[i] = f2b(Wh[(h * 128 + k) * 128 + n]);
  } else if (i < 90112) {                   // WLT (8 frags, 4 real + 4 zero)
    int t = i - 86016;
    int f = t >> 9;
    int k = (f & 3) * 32 + lh * 8 + j;
    ws[i] = f2b((f < 4 && lm < 2) ? WL[k * 2 + lm] : 0.f);
  }
}

// swish via exp2: u = z * -log2(e), e = 2^u, s = rcp(1+e), z*s.
__device__ __forceinline__ f32x4 swish4(f32x4 z) {
  const f32x4 u = z * (-1.44269504088896340736f);
  f32x4 e;
#if __has_builtin(__builtin_amdgcn_exp2f)
  e[0] = __builtin_amdgcn_exp2f(u[0]); e[1] = __builtin_amdgcn_exp2f(u[1]);
  e[2] = __builtin_amdgcn_exp2f(u[2]); e[3] = __builtin_amdgcn_exp2f(u[3]);
#else
  e[0] = __expf(u[0] * 0.6931471805599453f); e[1] = __expf(u[1] * 0.6931471805599453f);
  e[2] = __expf(u[2] * 0.6931471805599453f); e[3] = __expf(u[3] * 0.6931471805599453f);
#endif
  const f32x4 w = e + 1.f;
  f32x4 s;
  s[0] = __builtin_amdgcn_rcpf(w[0]); s[1] = __builtin_amdgcn_rcpf(w[1]);
  s[2] = __builtin_amdgcn_rcpf(w[2]); s[3] = __builtin_amdgcn_rcpf(w[3]);
  return z * s;
}

__device__ __forceinline__ uint2 pack4(f32x4 r) {   // v_cvt_pk_bf16_f32 path
  bf16x2 lo = {(__bf16)r[0], (__bf16)r[1]};
  bf16x2 hi = {(__bf16)r[2], (__bf16)r[3]};
  uint2 wv;
  wv.x = __builtin_bit_cast(unsigned int, lo);
  wv.y = __builtin_bit_cast(unsigned int, hi);
  return wv;
}

#define LRD(addr) __builtin_bit_cast(bf16x8, *reinterpret_cast<const uint4*>(addr))
#define MFMA(a, b, c) __builtin_amdgcn_mfma_f32_16x16x32_bf16((a), (b), (c), 0, 0, 0)

// Cooperative 8KB stage: 256 threads x 2 x 16B direct global->LDS.
__device__ __forceinline__ void stage8k(const char* src, char* dst, int tid) {
  const int woff = (tid >> 6) * 1024;    // wave-uniform LDS base
#if __has_builtin(__builtin_amdgcn_global_load_lds)
  __builtin_amdgcn_global_load_lds(
      (const __attribute__((address_space(1))) unsigned int*)(src + tid * 16),
      (__attribute__((address_space(3))) unsigned int*)(dst + woff), 16, 0, 0);
  __builtin_amdgcn_global_load_lds(
      (const __attribute__((address_space(1))) unsigned int*)(src + 4096 + tid * 16),
      (__attribute__((address_space(3))) unsigned int*)(dst + 4096 + woff), 16, 0, 0);
#else
  const uint4 v0 = *reinterpret_cast<const uint4*>(src + tid * 16);
  const uint4 v1 = *reinterpret_cast<const uint4*>(src + 4096 + tid * 16);
  *reinterpret_cast<uint4*>(dst + tid * 16) = v0;
  *reinterpret_cast<uint4*>(dst + 4096 + tid * 16) = v1;
#endif
}

// Channel-split: block = 64 points x 128 ch, 4 waves; wave w owns channel
// strip [w*32, w*32+32) for ALL 64 points -> acc[2 nt][4 pt-groups] = 32 AGPR.
// Shared weight stream double-buffered in LDS at ks (8KB) granularity.
// Hs is SHARED across waves -> every phase that reads Hs must be separated
// from the epilogue that writes Hs by a barrier (R11 bug: missing barrier
// between ks3 reads / L0 reads and the strip writes -> cross-wave race).
__launch_bounds__(256, 4)
__global__ void mlp_kernel(const float* __restrict__ X,
                           const float* __restrict__ nu_min_p,
                           const float* __restrict__ nu_max_p,
                           const float* __restrict__ b0,
                           const float* __restrict__ bh,
                           const float* __restrict__ bL,
                           const unsigned short* __restrict__ ws,
                           float* __restrict__ out) {
  __shared__ __align__(16) char smem[16384 + 16384 + 2560];
  char* Hs  = smem;                        // [64 pt][128 ch] bf16, swizzled
  char* wb0 = smem + 16384;                // shared weight buffers (8KB each)
  char* wb1 = smem + 24576;
  float* bias_lds = reinterpret_cast<float*>(smem + 32768);
  const int tid  = threadIdx.x;
  const int lane = tid & 63, wave = tid >> 6;
  const int lm = lane & 15, lh = lane >> 4;
  const int row0 = blockIdx.x * 64;
  const char* wsb = reinterpret_cast<const char*>(ws);
  const int xorm = (lm & 7) << 4;
  const int ntb = wave * 2;                // this wave's first nt
  // read addr per pt-group g: rd(g,ks) = vaG[g] ^ (ks<<6)
  int vaG[4], waG[4];
#pragma unroll
  for (int g = 0; g < 4; ++g) {
    vaG[g] = (g * 16 + lm) * 256 + ((lh * 16) ^ xorm);
    // write: logical col-bytes = wave<<6 | j<<5 | lh*8 (disjoint bits), ^xorm
    waG[g] = (g * 16 + lm) * 256 + (((lh * 8) ^ xorm) ^ (wave << 6));
  }

  // ---- prologue: stage L0 weights -> wb1; bias cache; inputs ----
  stage8k(wsb + WS_WT0_B, wb1, tid);
#pragma unroll
  for (int i = 0; i < 3; ++i) {
    const int idx = i * 256 + tid;
    if (idx < 640) bias_lds[idx] = bh[idx];
  }
  if (tid < 64) {
    const float4 xv = reinterpret_cast<const float4*>(X)[row0 + tid];
    const float numin = nu_min_p[0], numax = nu_max_p[0];
    const float v0 = xv.x;
    const float v1 = xv.y;
    const float v2 = 2.f * xv.z - 1.f;
    const float v3 = 2.f * (xv.w - numin) / (numax - numin) - 1.f;
    uint4 c0;
    c0.x = (unsigned)f2b(v0) | ((unsigned)f2b(v1) << 16);
    c0.y = (unsigned)f2b(v2) | ((unsigned)f2b(v3) << 16);
    c0.z = 0u; c0.w = 0u;
    const uint4 z4 = make_uint4(0u, 0u, 0u, 0u);
    const int xr = (tid & 7) << 4;
    char* rp = Hs + tid * 256;
    *reinterpret_cast<uint4*>(rp + (0  ^ xr)) = c0;
    *reinterpret_cast<uint4*>(rp + (16 ^ xr)) = z4;
    *reinterpret_cast<uint4*>(rp + (32 ^ xr)) = z4;
    *reinterpret_cast<uint4*>(rp + (48 ^ xr)) = z4;
  }
  __syncthreads();

  f32x4 acc[2][4];
  bf16x8 a0, a1;

  // ================= L0 : K=32, read wb1, stage h0ks0 -> wb0 =================
  {
    stage8k(wsb + WS_WTH_B, wb0, tid);
    a0 = LRD(wb1 + (ntb + 0) * 1024 + lane * 16);
    a1 = LRD(wb1 + (ntb + 1) * 1024 + lane * 16);
    const f32x4 bv0 = *reinterpret_cast<const f32x4*>(b0 + (ntb + 0) * 16 + lh * 4);
    const f32x4 bv1 = *reinterpret_cast<const f32x4*>(b0 + (ntb + 1) * 16 + lh * 4);
#pragma unroll
    for (int g = 0; g < 4; ++g) {
      const bf16x8 f = LRD(Hs + vaG[g]);
      acc[0][g] = MFMA(a0, f, bv0);
      acc[1][g] = MFMA(a1, f, bv1);
    }
    __syncthreads();   // all L0 reads of Hs done before strips are overwritten
#pragma unroll
    for (int j = 0; j < 2; ++j)
#pragma unroll
      for (int g = 0; g < 4; ++g) {
        const uint2 wv = pack4(swish4(acc[j][g]));
        *reinterpret_cast<uint2*>(Hs + (waG[g] ^ (j << 5))) = wv;
      }
    __syncthreads();
  }

  // phase: stage SRC->SBUF; aa from RBUF; 4 B-frags at KSOFF; 8 MFMA
#define HPHASE(RBUF, SBUF, SRC, KSOFF, C0, C1)                               \
  do {                                                                       \
    stage8k((SRC), (SBUF), tid);                                             \
    a0 = LRD((RBUF) + (ntb + 0) * 1024 + lane * 16);                         \
    a1 = LRD((RBUF) + (ntb + 1) * 1024 + lane * 16);                         \
    _Pragma("unroll")                                                        \
    for (int g = 0; g < 4; ++g) {                                            \
      const bf16x8 f = LRD(Hs + (vaG[g] ^ (KSOFF)));                         \
      acc[0][g] = MFMA(a0, f, (C0));                                         \
      acc[1][g] = MFMA(a1, f, (C1));                                         \
    }                                                                        \
  } while (0)

  // ============ 5 hidden layers : 4 shared-stage phases each ============
#pragma unroll 1
  for (int h = 0; h < 5; ++h) {
    const char* wsrc = wsb + WS_WTH_B + h * 32768;
    const char* nsrc = (h < 4) ? (wsrc + 32768) : (wsb + WS_WLT_B);
    const f32x4 bv0 = *reinterpret_cast<const f32x4*>(bias_lds + h * 128 + (ntb + 0) * 16 + lh * 4);
    const f32x4 bv1 = *reinterpret_cast<const f32x4*>(bias_lds + h * 128 + (ntb + 1) * 16 + lh * 4);

    HPHASE(wb0, wb1, wsrc + 8192,  0,   bv0, bv1);              // ks0 (stages ks1)
    __syncthreads();
    HPHASE(wb1, wb0, wsrc + 16384, 64,  acc[0][g], acc[1][g]);  // ks1 (stages ks2)
    __syncthreads();
    HPHASE(wb0, wb1, wsrc + 24576, 128, acc[0][g], acc[1][g]);  // ks2 (stages ks3)
    __syncthreads();
    HPHASE(wb1, wb0, nsrc,         192, acc[0][g], acc[1][g]);  // ks3 (stages next/WLT)
    __syncthreads();   // all ks3 reads of Hs done before strips are overwritten
    // epilogue: swish (bias already in acc) -> bf16 -> Hs
#pragma unroll
    for (int j = 0; j < 2; ++j)
#pragma unroll
      for (int g = 0; g < 4; ++g) {
        const uint2 wv = pack4(swish4(acc[j][g]));
        *reinterpret_cast<uint2*>(Hs + (waG[g] ^ (j << 5))) = wv;
      }
    __syncthreads();
  }
#undef HPHASE

  // ========== final layer : [128 -> 2]; weights in wb0; wave w -> pts w*16.. ==========
  {
    const float bl0 = bL[0], bl1 = bL[1];
    const int vaF = (wave * 16 + lm) * 256 + ((lh * 16) ^ xorm);
    f32x4 accL = {0.f, 0.f, 0.f, 0.f};
#pragma unroll
    for (int ks = 0; ks < 4; ++ks) {
      const bf16x8 a = LRD(wb0 + ks * 1024 + lane * 16);
      const bf16x8 f = LRD(Hs + (vaF ^ (ks << 6)));
      accL = MFMA(a, f, accL);
    }
    if (lh == 0) {
      const int p = wave * 16 + lm;
      float2 o;
      o.x = accL[0] + bl0;
      o.y = accL[1] + bl1;
      *reinterpret_cast<float2*>(out + (size_t)(row0 + p) * 2) = o;
    }
  }
}

extern "C" void kernel_launch(void* const* d_in, const int* in_sizes, int n_in,
                              void* d_out, int out_size, void* d_ws, size_t ws_size,
                              hipStream_t stream) {
  const float* X     = (const float*)d_in[0];
  const float* numin = (const float*)d_in[1];
  const float* numax = (const float*)d_in[2];
  const float* W0    = (const float*)d_in[3];
  const float* b0    = (const float*)d_in[4];
  const float* Wh    = (const float*)d_in[5];
  const float* bh    = (const float*)d_in[6];
  const float* WL    = (const float*)d_in[7];
  const float* bL    = (const float*)d_in[8];
  unsigned short* ws = (unsigned short*)d_ws;
  float* out = (float*)d_out;

  hipLaunchKernelGGL(prep_kernel, dim3(352), dim3(256), 0, stream, W0, Wh, WL, ws);
  hipLaunchKernelGGL(mlp_kernel, dim3(4096), dim3(256), 0, stream,
                     X, numin, numax, b0, bh, bL, ws, out);
}